// Round 9
// baseline (45327.405 us; speedup 1.0000x reference)
//
#include <hip/hip_runtime.h>
#include <math.h>

#define BATCH 128
#define TSTEPS 1024
#define INSZ 256
#define HSZ 256
#define MEMN 128

#define NWG_A 64   // A WGs (XCD0)
#define NWG_B 64
#define NWG_C 32
#define NTHR 256

#define GATE_C 0.40131233988754794f
#define OMG_C  (1.0f - GATE_C)
#define GAMMA_C 0.3f

// ---- per-step state, unique slot per t ----
__device__ float g_zx[(size_t)TSTEPS * 4 * HSZ * BATCH];  // zx(t)[g][j][b] = x@Wih^T + biases
__device__ float g_hL[(size_t)TSTEPS * BATCH * HSZ];      // h(t)[b][j]  PLAIN (XCD0-local)
__device__ float g_hB[(size_t)TSTEPS * BATCH * HSZ];      // h(t)[b][j]  WT (for B)
__device__ float g_hT[(size_t)TSTEPS * HSZ * BATCH];      // hT(t)[j][b] WT (for C)
__device__ float g_M [(size_t)TSTEPS * MEMN * HSZ];       // M(t)[m][j], slots 1..1023 (WT)
__device__ float g_Mn[(size_t)TSTEPS * MEMN];             // Mn(t)[m] (WT)
__device__ float g_ww[(size_t)TSTEPS * BATCH * MEMN];     // ww(t)[b][m], slots 1..1023 (WT)
// flags
__device__ int g_fAL[TSTEPS * NWG_A];  // A-local (XCD0 L2, plain/volatile)
__device__ int g_fA [TSTEPS * NWG_A];  // A-remote (MALL), deferred one iter
__device__ int g_fB [TSTEPS * NWG_B];
__device__ int g_fC [TSTEPS * NWG_C];

__global__ void reset_ctrl_kernel() {
    const int gt = blockIdx.x * 256 + threadIdx.x, gn = gridDim.x * 256;
    for (int i = gt; i < TSTEPS * NWG_A; i += gn) { g_fAL[i] = 0; g_fA[i] = 0; }
    for (int i = gt; i < TSTEPS * NWG_B; i += gn) g_fB[i] = 0;
    for (int i = gt; i < TSTEPS * NWG_C; i += gn) g_fC[i] = 0;
}

__device__ __forceinline__ float sigf(float x) { return 1.0f / (1.0f + expf(-x)); }
__device__ __forceinline__ void st_wt(float* p, float v) {
    __hip_atomic_store(p, v, __ATOMIC_RELAXED, __HIP_MEMORY_SCOPE_AGENT);
}
__device__ __forceinline__ void st_flag(int* p, int v) {
    __hip_atomic_store(p, v, __ATOMIC_RELAXED, __HIP_MEMORY_SCOPE_AGENT);
}
__device__ __forceinline__ void wait_vm0() { asm volatile("s_waitcnt vmcnt(0)" ::: "memory"); }

// agent-scope wave scan (MALL) — for cross-XCD flags
__device__ __forceinline__ void wait_flags(int* f, int n, int want, int lane) {
    int it = 0;
    for (;;) {
        bool ok = true;
        for (int i = lane; i < n; i += 64)
            ok &= (__hip_atomic_load(&f[i], __ATOMIC_RELAXED, __HIP_MEMORY_SCOPE_AGENT) == want);
        if (__all(ok)) break;
        __builtin_amdgcn_s_sleep(1);
        if (++it > (1 << 22)) break;
    }
}
// XCD-local poll: volatile (L1-bypass -> local L2) + periodic agent-scope fallback
__device__ __forceinline__ void wait_local(int* f, int want, int lane) {
    volatile int* vf = (volatile int*)f;
    int it = 0;
    for (;;) {
        int v = vf[lane];
        if ((it & 255) == 255)
            v = __hip_atomic_load(&f[lane], __ATOMIC_RELAXED, __HIP_MEMORY_SCOPE_AGENT);
        if (__all(v == want)) break;
        __builtin_amdgcn_s_sleep(1);
        if (++it > (1 << 22)) break;
    }
}

// ================= precompute: zx[t][g][j][b] = X(t,b)@Wih[g*H+j] + bih + bhh =================
__global__ void __launch_bounds__(NTHR, 2)
pre_kernel(const float* __restrict__ X, const float* __restrict__ Wih,
           const float* __restrict__ bih, const float* __restrict__ bhh) {
    __shared__ float4 p_x[4096];  // [64 b][64 c] swizzled, 64 KB
    const int w = blockIdx.x, tid = threadIdx.x;
    const int t = w >> 1, half = w & 1;
#pragma unroll
    for (int rep = 0; rep < 16; ++rep) {
        const int idx = rep * 256 + tid;
        const int bl = idx >> 6, c = idx & 63;
        p_x[bl * 64 + (c ^ bl)] =
            *(const float4*)&X[((size_t)(half * 64 + bl) * TSTEPS + t) * INSZ + c * 4];
    }
    __syncthreads();
    const int bl = tid & 63, hf2 = tid >> 6;
    const int b = half * 64 + bl;
    const float4* wih4 = (const float4*)Wih;
    for (int jb4 = 0; jb4 < 16; ++jb4) {
        float a16[16];
#pragma unroll
        for (int i = 0; i < 16; ++i) a16[i] = 0.f;
#pragma unroll 4
        for (int c = 0; c < 64; ++c) {
            const float4 xv = p_x[bl * 64 + (c ^ bl)];
#pragma unroll
            for (int g = 0; g < 4; ++g)
#pragma unroll
                for (int j4 = 0; j4 < 4; ++j4) {
                    const int row = g * HSZ + hf2 * 64 + jb4 * 4 + j4;
                    const float4 wv4 = wih4[(size_t)row * 64 + c];
                    a16[g * 4 + j4] += wv4.x * xv.x + wv4.y * xv.y + wv4.z * xv.z + wv4.w * xv.w;
                }
        }
#pragma unroll
        for (int g = 0; g < 4; ++g)
#pragma unroll
            for (int j4 = 0; j4 < 4; ++j4) {
                const int j = hf2 * 64 + jb4 * 4 + j4;
                const int row = g * HSZ + j;
                g_zx[(((size_t)t * 4 + g) * HSZ + j) * BATCH + b] =
                    a16[g * 4 + j4] + bih[row] + bhh[row];
            }
    }
}

// ================= persistent: A (XCD0-local) + B + C =================
__global__ void __launch_bounds__(NTHR, 2)
mann_persist(const float* __restrict__ Whh, float* __restrict__ out) {
    __shared__ float4 s_h4[4096];   // A: h(t-1) half-batch [64 b][64 c] swizzled (64 KB)
    __shared__ float s_aux[1024];   // B: s_h2[512]+s_wr2[256]; C: s_wwc[512]
    __shared__ float s_tr[512];     // A: h publish staging [8 j][64 b]
    __shared__ float s_red8[8];
    __shared__ float s_red16[16];
    __shared__ unsigned long long s_redu8[8];

    const int w = blockIdx.x, tid = threadIdx.x;
    const int lane = tid & 63, wv = tid >> 6;
    const int cls = w & 7, slot = w >> 3;

    auto grpsum = [&](float v) -> float {
#pragma unroll
        for (int o = 32; o; o >>= 1) v += __shfl_xor(v, o, 64);
        if (lane == 0) s_red8[wv] = v;
        __syncthreads();
        float r = s_red8[(tid >> 7) * 2] + s_red8[(tid >> 7) * 2 + 1];
        __syncthreads();
        return r;
    };
    auto grpmax = [&](float v) -> float {
#pragma unroll
        for (int o = 32; o; o >>= 1) v = fmaxf(v, __shfl_xor(v, o, 64));
        if (lane == 0) s_red8[wv] = v;
        __syncthreads();
        float r = fmaxf(s_red8[(tid >> 7) * 2], s_red8[(tid >> 7) * 2 + 1]);
        __syncthreads();
        return r;
    };
    auto grpminu = [&](unsigned long long v) -> unsigned long long {
#pragma unroll
        for (int o = 32; o; o >>= 1) {
            unsigned long long o2 = __shfl_xor(v, o, 64);
            v = (o2 < v) ? o2 : v;
        }
        if (lane == 0) s_redu8[wv] = v;
        __syncthreads();
        unsigned long long a = s_redu8[(tid >> 7) * 2], b2 = s_redu8[(tid >> 7) * 2 + 1];
        unsigned long long r = (a < b2) ? a : b2;
        __syncthreads();
        return r;
    };
    auto red256sum4 = [&](float v0, float v1, float v2, float v3, float (&r)[4]) {
#pragma unroll
        for (int o = 32; o; o >>= 1) {
            v0 += __shfl_xor(v0, o, 64);
            v1 += __shfl_xor(v1, o, 64);
            v2 += __shfl_xor(v2, o, 64);
            v3 += __shfl_xor(v3, o, 64);
        }
        if (lane == 0) {
            s_red16[wv * 4 + 0] = v0; s_red16[wv * 4 + 1] = v1;
            s_red16[wv * 4 + 2] = v2; s_red16[wv * 4 + 3] = v3;
        }
        __syncthreads();
#pragma unroll
        for (int k = 0; k < 4; ++k)
            r[k] = (s_red16[0 * 4 + k] + s_red16[1 * 4 + k]) +
                   (s_red16[2 * 4 + k] + s_red16[3 * 4 + k]);
        __syncthreads();
    };

    if (cls == 0) {
        // ============ A: h(t) = LSTM(h(t-1)); entirely XCD0-local ============
        const int jblk = slot >> 1, bhalf = slot & 1;
        const int J = jblk * 8;
        const int g2 = wv;
        const int bglob = bhalf * 64 + lane;
        const float4* wh4 = (const float4*)Whh;
        float creg[2] = {0.f, 0.f};

        for (int t = 0; t < TSTEPS; ++t) {
            // zx prefetch (independent of flags; issued first, consumed last)
            float zr[2][4];
#pragma unroll
            for (int jj = 0; jj < 2; ++jj) {
                const int j = J + g2 * 2 + jj;
#pragma unroll
                for (int g = 0; g < 4; ++g)
                    zr[jj][g] = g_zx[(((size_t)t * 4 + g) * HSZ + j) * BATCH + bglob];
            }
            if (t > 0) {
                if (wv == 0) wait_local(g_fAL + (size_t)(t - 1) * NWG_A, t, lane);
                __syncthreads();
                asm volatile("" ::: "memory");
                // stage own 64-batch half of h(t-1) from LOCAL L2 -> LDS (swizzled)
#pragma unroll
                for (int rep = 0; rep < 16; ++rep) {
                    const int idx = rep * 256 + tid;
                    const int bl = idx >> 6, c = idx & 63;
                    const float4 v = *(const float4*)
                        &g_hL[((size_t)(t - 1) * BATCH + bhalf * 64 + bl) * HSZ + c * 4];
                    s_h4[bl * 64 + (c ^ bl)] = v;
                }
                __syncthreads();
            }
            float acc[2][4] = {{0.f, 0.f, 0.f, 0.f}, {0.f, 0.f, 0.f, 0.f}};
            if (t > 0) {
                const int r0 = J + g2 * 2;
#pragma unroll 8
                for (int c = 0; c < 64; ++c) {
                    const float4 xv = s_h4[lane * 64 + (c ^ lane)];
#pragma unroll
                    for (int jj = 0; jj < 2; ++jj)
#pragma unroll
                        for (int g = 0; g < 4; ++g) {
                            const float4 wv4 = wh4[(size_t)(g * HSZ + r0 + jj) * 64 + c];
                            acc[jj][g] += wv4.x * xv.x + wv4.y * xv.y + wv4.z * xv.z + wv4.w * xv.w;
                        }
                }
            }
#pragma unroll
            for (int jj = 0; jj < 2; ++jj) {
                const float z0 = zr[jj][0] + acc[jj][0];
                const float z1 = zr[jj][1] + acc[jj][1];
                const float z2 = zr[jj][2] + acc[jj][2];
                const float z3 = zr[jj][3] + acc[jj][3];
                const float cn = sigf(z1) * creg[jj] + sigf(z0) * tanhf(z2);
                const float hn = sigf(z3) * tanhf(cn);
                creg[jj] = cn;
                s_tr[(g2 * 2 + jj) * 64 + lane] = hn;
            }
            __syncthreads();
            if (tid < 64) {  // publish local copy (plain stores -> XCD0 L2)
                const int b = bhalf * 64 + tid;
                float4 lo, hi;
                lo.x = s_tr[0 * 64 + tid]; lo.y = s_tr[1 * 64 + tid];
                lo.z = s_tr[2 * 64 + tid]; lo.w = s_tr[3 * 64 + tid];
                hi.x = s_tr[4 * 64 + tid]; hi.y = s_tr[5 * 64 + tid];
                hi.z = s_tr[6 * 64 + tid]; hi.w = s_tr[7 * 64 + tid];
                *(float4*)&g_hL[((size_t)t * BATCH + b) * HSZ + J] = lo;
                *(float4*)&g_hL[((size_t)t * BATCH + b) * HSZ + J + 4] = hi;
            }
            wait_vm0();  // drains: local h(t) stores + PREVIOUS iter's WT stores
            __syncthreads();
            if (tid == 0) {
                *(volatile int*)&g_fAL[(size_t)t * NWG_A + slot] = t + 1;        // local flag
                if (t > 0) st_flag(&g_fA[(size_t)(t - 1) * NWG_A + slot], t);    // remote, deferred
            }
            if (tid < 64) {  // remote WT copies (fire-and-forget; drained next iter)
                const int b = bhalf * 64 + tid;
#pragma unroll
                for (int jj = 0; jj < 8; ++jj) {
                    const float hv = s_tr[jj * 64 + tid];
                    st_wt(&g_hB[((size_t)t * BATCH + b) * HSZ + J + jj], hv);
                    st_wt(&g_hT[((size_t)t * HSZ + J + jj) * BATCH + b], hv);
                }
            }
        }
        wait_vm0();
        if (tid == 0) st_flag(&g_fA[(size_t)(TSTEPS - 1) * NWG_A + slot], TSTEPS);
    } else if (cls == 1) {
        // ============ B: read head + output + w_u/w_w (R4-proven numerics) ============
        const int bwg = slot;  // 0..63
        const int grp = tid >> 7, lm = tid & 127;
        const int bB = bwg * 2 + grp;
        float* s_h2 = s_aux;
        float* s_wr2 = s_aux + 512;
        float wwreg = (lm == 0) ? OMG_C : 0.f;
        float wureg = 0.f;

        for (int t = 0; t < TSTEPS; ++t) {
            if (wv == 0) wait_flags(g_fA + (size_t)t * NWG_A, NWG_A, t + 1, lane);
            else if (wv == 1 && t > 0) wait_flags(g_fC + (size_t)(t - 1) * NWG_C, NWG_C, t, lane);
            __syncthreads();
            asm volatile("" ::: "memory");
            s_h2[grp * 256 + lm] = g_hB[((size_t)t * BATCH + bB) * HSZ + lm];
            s_h2[grp * 256 + lm + 128] = g_hB[((size_t)t * BATCH + bB) * HSZ + 128 + lm];
            __syncthreads();
            const float hv0 = s_h2[grp * 256 + lm], hv1 = s_h2[grp * 256 + lm + 128];
            const float hnorm = sqrtf(grpsum(hv0 * hv0 + hv1 * hv1));
            float sc = 0.f;
            if (t > 0) {
                const float4* mrow = (const float4*)&g_M[((size_t)t * MEMN + lm) * HSZ];
                const float4* h4 = (const float4*)&s_h2[grp * 256];
                float a = 0.f;
#pragma unroll 8
                for (int c = 0; c < 64; ++c) {
                    const float4 m4 = mrow[c], x4 = h4[c];
                    a += m4.x * x4.x + m4.y * x4.y + m4.z * x4.z + m4.w * x4.w;
                }
                const float mn = g_Mn[(size_t)t * MEMN + lm];
                sc = a / (hnorm * mn + 1e-8f);
            }
            const float mx = grpmax(sc);
            const float ev = expf(sc - mx);
            const float es = grpsum(ev);
            const float wr = ev / es;
            s_wr2[grp * 128 + lm] = wr;
            __syncthreads();
            float rd0 = 0.f, rd1 = 0.f;
            if (t > 0) {
#pragma unroll 8
                for (int m = 0; m < 128; ++m) {
                    const float mv = g_M[((size_t)t * MEMN + m) * HSZ + tid];
                    rd0 += s_wr2[m] * mv;
                    rd1 += s_wr2[128 + m] * mv;
                }
            }
            const int b0 = bwg * 2, b1 = b0 + 1;
            float* o0 = out + ((size_t)b0 * TSTEPS + t) * 512;
            float* o1 = out + ((size_t)b1 * TSTEPS + t) * 512;
            o0[tid] = s_h2[tid];
            o1[tid] = s_h2[256 + tid];
            o0[256 + tid] = rd0;
            o1[256 + tid] = rd1;
            const float un = GAMMA_C * wureg + wr + wwreg;
            const float un2 = grpsum(un * un);
            const float us = 1.0f / fmaxf(sqrtf(un2), 1e-12f);
            const float wun = un * us;
            wureg = wun;
            unsigned long long key =
                (((unsigned long long)__float_as_uint(wun)) << 32) | (unsigned)lm;
            const unsigned long long mk = grpminu(key);
            const int amin = (int)(mk & 0xffffffffu);
            const float wwn = GATE_C * wr + ((lm == amin) ? OMG_C : 0.f);
            wwreg = wwn;
            if (t + 1 < TSTEPS)
                st_wt(&g_ww[((size_t)(t + 1) * BATCH + bB) * MEMN + lm], wwn);
            wait_vm0();
            __syncthreads();
            if (tid == 0) st_flag(&g_fB[(size_t)t * NWG_B + bwg], t + 1);
        }
    } else if (cls == 3 && slot < NWG_C) {
        // ============ C: M(t+1) = l2norm(M(t) + ww(t)^T h(t)) ============
        const int cwg = slot;
        const int m0 = cwg * 4;
        float* s_wwc = s_aux;  // [4][128]
        float mreg[4] = {0.f, 0.f, 0.f, 0.f};

        for (int t = 0; t < TSTEPS - 1; ++t) {
            if (wv == 1 && t > 0) wait_flags(g_fB + (size_t)(t - 1) * NWG_B, NWG_B, t, lane);
            __syncthreads();
            asm volatile("" ::: "memory");
            {
                const int e0 = tid, e1 = tid + 256;
                float v0, v1;
                if (t > 0) {
                    v0 = g_ww[((size_t)t * BATCH + (e0 >> 2)) * MEMN + m0 + (e0 & 3)];
                    v1 = g_ww[((size_t)t * BATCH + (e1 >> 2)) * MEMN + m0 + (e1 & 3)];
                } else {
                    v0 = (m0 + (e0 & 3) == 0) ? OMG_C : 0.f;
                    v1 = (m0 + (e1 & 3) == 0) ? OMG_C : 0.f;
                }
                s_wwc[(e0 & 3) * 128 + (e0 >> 2)] = v0;
                s_wwc[(e1 & 3) * 128 + (e1 >> 2)] = v1;
            }
            if (wv == 0) wait_flags(g_fA + (size_t)t * NWG_A, NWG_A, t + 1, lane);
            __syncthreads();
            asm volatile("" ::: "memory");
            float4 hb[32];
            const float4* ht4 = (const float4*)&g_hT[((size_t)t * HSZ + tid) * BATCH];
#pragma unroll
            for (int q = 0; q < 32; ++q) hb[q] = ht4[q];
            float macc[4];
#pragma unroll
            for (int mi = 0; mi < 4; ++mi) macc[mi] = mreg[mi];
#pragma unroll
            for (int b4 = 0; b4 < 32; ++b4) {
                const float4 hv4 = hb[b4];
#pragma unroll
                for (int mi = 0; mi < 4; ++mi) {
                    const float* wc = &s_wwc[mi * 128 + b4 * 4];
                    macc[mi] += wc[0] * hv4.x + wc[1] * hv4.y + wc[2] * hv4.z + wc[3] * hv4.w;
                }
            }
            float nr[4];
            red256sum4(macc[0] * macc[0], macc[1] * macc[1],
                       macc[2] * macc[2], macc[3] * macc[3], nr);
#pragma unroll
            for (int mi = 0; mi < 4; ++mi) {
                const float nrm = sqrtf(nr[mi]);
                const float scale = 1.0f / fmaxf(nrm, 1e-12f);
                const float vo = macc[mi] * scale;
                mreg[mi] = vo;
                st_wt(&g_M[((size_t)(t + 1) * MEMN + m0 + mi) * HSZ + tid], vo);
                if (tid == 0) st_wt(&g_Mn[(size_t)(t + 1) * MEMN + m0 + mi], nrm * scale);
            }
            wait_vm0();
            __syncthreads();
            if (tid == 0) st_flag(&g_fC[(size_t)t * NWG_C + cwg], t + 1);
        }
    }
    // other classes: exit immediately
}

extern "C" void kernel_launch(void* const* d_in, const int* in_sizes, int n_in,
                              void* d_out, int out_size, void* d_ws, size_t ws_size,
                              hipStream_t stream) {
    const float* X   = (const float*)d_in[0];
    const float* Wih = (const float*)d_in[1];
    const float* Whh = (const float*)d_in[2];
    const float* bih = (const float*)d_in[3];
    const float* bhh = (const float*)d_in[4];
    float* out = (float*)d_out;
    (void)in_sizes; (void)n_in; (void)out_size; (void)d_ws; (void)ws_size;

    hipLaunchKernelGGL(reset_ctrl_kernel, dim3(256), dim3(256), 0, stream);
    hipLaunchKernelGGL(pre_kernel, dim3(2048), dim3(NTHR), 0, stream, X, Wih, bih, bhh);
    hipLaunchKernelGGL(mann_persist, dim3(512), dim3(NTHR), 0, stream, Whh, out);
}

// Round 10
// 25458.067 us; speedup vs baseline: 1.7805x; 1.7805x over previous
//
#include <hip/hip_runtime.h>
#include <math.h>

#define BATCH 128
#define TSTEPS 1024
#define INSZ 256
#define HSZ 256
#define MEMN 128

#define NWG_A 64
#define NWG_B 64
#define NWG_C 32
#define NWG 160
#define NTHR 256
#define FSP 16   // flag spread (ints) -> 64B apart

#define GATE_C 0.40131233988754794f
#define OMG_C  (1.0f - GATE_C)
#define GAMMA_C 0.3f

// ---- per-step state, unique slot per t (WT-produced, cached-read consumed) ----
__device__ float g_zx [(size_t)TSTEPS * 4 * HSZ * BATCH];  // zx(t)[g][j][b]
__device__ float g_hB [(size_t)TSTEPS * BATCH * HSZ];      // h(t)[b][j]
__device__ float g_hT [(size_t)TSTEPS * HSZ * BATCH];      // hT(t)[j][b]
__device__ float g_M  [(size_t)TSTEPS * MEMN * HSZ];       // M(t), slots 1..1023
__device__ float g_Mn [(size_t)TSTEPS * MEMN];
__device__ float g_wwT[(size_t)TSTEPS * MEMN * BATCH];     // wwT(t)[m][b], slots 1..1023
__device__ int g_fA[TSTEPS * NWG_A * FSP];
__device__ int g_fB[TSTEPS * NWG_B * FSP];
__device__ int g_fC[TSTEPS * NWG_C * FSP];

__global__ void reset_ctrl_kernel() {
    const int gt = blockIdx.x * 256 + threadIdx.x, gn = gridDim.x * 256;
    for (int i = gt; i < TSTEPS * NWG_A * FSP; i += gn)
        __hip_atomic_store(&g_fA[i], 0, __ATOMIC_RELAXED, __HIP_MEMORY_SCOPE_AGENT);
    for (int i = gt; i < TSTEPS * NWG_B * FSP; i += gn)
        __hip_atomic_store(&g_fB[i], 0, __ATOMIC_RELAXED, __HIP_MEMORY_SCOPE_AGENT);
    for (int i = gt; i < TSTEPS * NWG_C * FSP; i += gn)
        __hip_atomic_store(&g_fC[i], 0, __ATOMIC_RELAXED, __HIP_MEMORY_SCOPE_AGENT);
}

__device__ __forceinline__ float sigf(float x) { return 1.0f / (1.0f + expf(-x)); }
__device__ __forceinline__ void st_wt(float* p, float v) {
    __hip_atomic_store(p, v, __ATOMIC_RELAXED, __HIP_MEMORY_SCOPE_AGENT);
}
__device__ __forceinline__ void st_wt2(float* p, float lo, float hi) {
    unsigned long long pk = (unsigned long long)__float_as_uint(lo) |
                            ((unsigned long long)__float_as_uint(hi) << 32);
    __hip_atomic_store((unsigned long long*)p, pk, __ATOMIC_RELAXED, __HIP_MEMORY_SCOPE_AGENT);
}
__device__ __forceinline__ void st_flag(int* p, int v) {
    __hip_atomic_store(p, v, __ATOMIC_RELAXED, __HIP_MEMORY_SCOPE_AGENT);
}
__device__ __forceinline__ void wait_vm0() { asm volatile("s_waitcnt vmcnt(0)" ::: "memory"); }

// wave scan over spread flags; slow poll cadence to avoid MALL line contention
__device__ __forceinline__ void wait_flags16(int* f, int n, int want, int lane) {
    int it = 0;
    for (;;) {
        bool ok = true;
        for (int i = lane; i < n; i += 64)
            ok &= (__hip_atomic_load(&f[i * FSP], __ATOMIC_RELAXED, __HIP_MEMORY_SCOPE_AGENT) == want);
        if (__all(ok)) break;
        __builtin_amdgcn_s_sleep(12);
        if (++it > (1 << 20)) break;  // hang valve
    }
}

// ================= zx precompute (R9-verified) =================
__global__ void __launch_bounds__(NTHR, 2)
pre_kernel(const float* __restrict__ X, const float* __restrict__ Wih,
           const float* __restrict__ bih, const float* __restrict__ bhh) {
    __shared__ float4 p_x[4096];
    const int w = blockIdx.x, tid = threadIdx.x;
    const int t = w >> 1, half = w & 1;
#pragma unroll
    for (int rep = 0; rep < 16; ++rep) {
        const int idx = rep * 256 + tid;
        const int bl = idx >> 6, c = idx & 63;
        p_x[bl * 64 + (c ^ bl)] =
            *(const float4*)&X[((size_t)(half * 64 + bl) * TSTEPS + t) * INSZ + c * 4];
    }
    __syncthreads();
    const int bl = tid & 63, hf2 = tid >> 6;
    const int b = half * 64 + bl;
    const float4* wih4 = (const float4*)Wih;
    for (int jb4 = 0; jb4 < 16; ++jb4) {
        float a16[16];
#pragma unroll
        for (int i = 0; i < 16; ++i) a16[i] = 0.f;
#pragma unroll 4
        for (int c = 0; c < 64; ++c) {
            const float4 xv = p_x[bl * 64 + (c ^ bl)];
#pragma unroll
            for (int g = 0; g < 4; ++g)
#pragma unroll
                for (int j4 = 0; j4 < 4; ++j4) {
                    const int row = g * HSZ + hf2 * 64 + jb4 * 4 + j4;
                    const float4 wv4 = wih4[(size_t)row * 64 + c];
                    a16[g * 4 + j4] += wv4.x * xv.x + wv4.y * xv.y + wv4.z * xv.z + wv4.w * xv.w;
                }
        }
#pragma unroll
        for (int g = 0; g < 4; ++g)
#pragma unroll
            for (int j4 = 0; j4 < 4; ++j4) {
                const int j = hf2 * 64 + jb4 * 4 + j4;
                const int row = g * HSZ + j;
                g_zx[(((size_t)t * 4 + g) * HSZ + j) * BATCH + b] =
                    a16[g * 4 + j4] + bih[row] + bhh[row];
            }
    }
}

// ================= persistent A/B/C =================
__global__ void __launch_bounds__(NTHR, 1)
mann_persist(const float* __restrict__ Whh, float* __restrict__ out) {
    __shared__ float4 s_big[8192];   // A: s_h4 (64KB used); B: s_M (128 KB)
    __shared__ float s_aux[1024];    // B: s_h2+s_wr2; C: s_wwc
    __shared__ float s_tr[512];      // A: publish staging [8 j][64 b]
    __shared__ float s_red8[8];
    __shared__ float s_red16[16];
    __shared__ unsigned long long s_redu8[8];

    const int w = blockIdx.x, tid = threadIdx.x;
    const int lane = tid & 63, wv = tid >> 6;

    auto grpsum = [&](float v) -> float {
#pragma unroll
        for (int o = 32; o; o >>= 1) v += __shfl_xor(v, o, 64);
        if (lane == 0) s_red8[wv] = v;
        __syncthreads();
        float r = s_red8[(tid >> 7) * 2] + s_red8[(tid >> 7) * 2 + 1];
        __syncthreads();
        return r;
    };
    auto grpmax = [&](float v) -> float {
#pragma unroll
        for (int o = 32; o; o >>= 1) v = fmaxf(v, __shfl_xor(v, o, 64));
        if (lane == 0) s_red8[wv] = v;
        __syncthreads();
        float r = fmaxf(s_red8[(tid >> 7) * 2], s_red8[(tid >> 7) * 2 + 1]);
        __syncthreads();
        return r;
    };
    auto grpminu = [&](unsigned long long v) -> unsigned long long {
#pragma unroll
        for (int o = 32; o; o >>= 1) {
            unsigned long long o2 = __shfl_xor(v, o, 64);
            v = (o2 < v) ? o2 : v;
        }
        if (lane == 0) s_redu8[wv] = v;
        __syncthreads();
        unsigned long long a = s_redu8[(tid >> 7) * 2], b2 = s_redu8[(tid >> 7) * 2 + 1];
        unsigned long long r = (a < b2) ? a : b2;
        __syncthreads();
        return r;
    };
    auto red256sum4 = [&](float v0, float v1, float v2, float v3, float (&r)[4]) {
#pragma unroll
        for (int o = 32; o; o >>= 1) {
            v0 += __shfl_xor(v0, o, 64);
            v1 += __shfl_xor(v1, o, 64);
            v2 += __shfl_xor(v2, o, 64);
            v3 += __shfl_xor(v3, o, 64);
        }
        if (lane == 0) {
            s_red16[wv * 4 + 0] = v0; s_red16[wv * 4 + 1] = v1;
            s_red16[wv * 4 + 2] = v2; s_red16[wv * 4 + 3] = v3;
        }
        __syncthreads();
#pragma unroll
        for (int k = 0; k < 4; ++k)
            r[k] = (s_red16[0 * 4 + k] + s_red16[1 * 4 + k]) +
                   (s_red16[2 * 4 + k] + s_red16[3 * 4 + k]);
        __syncthreads();
    };

    if (w < NWG_A) {
        // ====== A: h(t) = LSTM(zx(t), h(t-1)); half-local gather ======
        const int bb = w >> 5, jb = w & 31;
        const int J = jb * 8;
        const int jA = J + wv * 2;            // this wave's 2 j-rows
        const int bglob = bb * 64 + lane;     // this lane's batch
        float4* s_h4 = s_big;                 // [64 b][64 c4] swizzled
        float creg0 = 0.f, creg1 = 0.f;
        float zxr[8];
#pragma unroll
        for (int g = 0; g < 4; ++g)
#pragma unroll
            for (int jj = 0; jj < 2; ++jj)
                zxr[g * 2 + jj] = g_zx[((size_t)(0 * 4 + g) * HSZ + jA + jj) * BATCH + bglob];

        for (int t = 0; t < TSTEPS; ++t) {
            if (t > 0) {
                if (wv == 0)
                    wait_flags16(g_fA + ((size_t)(t - 1) * NWG_A + bb * 32) * FSP, 32, t, lane);
                __syncthreads();
                asm volatile("" ::: "memory");
#pragma unroll
                for (int rep = 0; rep < 16; ++rep) {  // stage own half's h(t-1): 64 KB
                    const int id = rep * 256 + tid, b = id >> 6, c = id & 63;
                    s_h4[b * 64 + (c ^ (b & 7))] =
                        *(const float4*)&g_hB[((size_t)(t - 1) * BATCH + bb * 64 + b) * HSZ + c * 4];
                }
                __syncthreads();
            }
            float acc[8] = {0.f, 0.f, 0.f, 0.f, 0.f, 0.f, 0.f, 0.f};
            if (t > 0) {
#pragma unroll 8
                for (int c = 0; c < 64; ++c) {
                    const float4 xv = s_h4[lane * 64 + (c ^ (lane & 7))];
#pragma unroll
                    for (int g = 0; g < 4; ++g)
#pragma unroll
                        for (int jj = 0; jj < 2; ++jj) {
                            const float4 w4 =
                                *(const float4*)&Whh[(size_t)(g * HSZ + jA + jj) * HSZ + c * 4];
                            acc[g * 2 + jj] += w4.x * xv.x + w4.y * xv.y + w4.z * xv.z + w4.w * xv.w;
                        }
                }
            }
#pragma unroll
            for (int jj = 0; jj < 2; ++jj) {
                const float z0 = zxr[0 * 2 + jj] + acc[0 * 2 + jj];
                const float z1 = zxr[1 * 2 + jj] + acc[1 * 2 + jj];
                const float z2 = zxr[2 * 2 + jj] + acc[2 * 2 + jj];
                const float z3 = zxr[3 * 2 + jj] + acc[3 * 2 + jj];
                float cr = jj ? creg1 : creg0;
                const float cn = sigf(z1) * cr + sigf(z0) * tanhf(z2);
                const float hn = sigf(z3) * tanhf(cn);
                if (jj) creg1 = cn; else creg0 = cn;
                s_tr[(wv * 2 + jj) * 64 + lane] = hn;
            }
            __syncthreads();
            if (tid < 128) {
                {   // b-major publish: b = tid>>1, q = tid&1 -> 4 dwords
                    const int b = tid >> 1, q = tid & 1;
                    const float v0 = s_tr[(q * 4 + 0) * 64 + b];
                    const float v1 = s_tr[(q * 4 + 1) * 64 + b];
                    const float v2 = s_tr[(q * 4 + 2) * 64 + b];
                    const float v3 = s_tr[(q * 4 + 3) * 64 + b];
                    float* dst = &g_hB[((size_t)t * BATCH + bb * 64 + b) * HSZ + J + q * 4];
                    st_wt2(dst, v0, v1);
                    st_wt2(dst + 2, v2, v3);
                }
                {   // j-major publish: j = tid>>4, c = tid&15 -> 4 dwords
                    const int j = tid >> 4, c = tid & 15;
                    const float v0 = s_tr[j * 64 + c * 4 + 0];
                    const float v1 = s_tr[j * 64 + c * 4 + 1];
                    const float v2 = s_tr[j * 64 + c * 4 + 2];
                    const float v3 = s_tr[j * 64 + c * 4 + 3];
                    float* dst = &g_hT[((size_t)t * HSZ + J + j) * BATCH + bb * 64 + c * 4];
                    st_wt2(dst, v0, v1);
                    st_wt2(dst + 2, v2, v3);
                }
            }
            wait_vm0();
            __syncthreads();
            if (tid == 0) st_flag(&g_fA[((size_t)t * NWG_A + w) * FSP], t + 1);
            if (t + 1 < TSTEPS) {  // zx(t+1) prefetch (virgin HBM stream, off critical path)
#pragma unroll
                for (int g = 0; g < 4; ++g)
#pragma unroll
                    for (int jj = 0; jj < 2; ++jj)
                        zxr[g * 2 + jj] =
                            g_zx[((size_t)((t + 1) * 4 + g) * HSZ + jA + jj) * BATCH + bglob];
            }
        }
    } else if (w < NWG_A + NWG_B) {
        // ====== B: read head + output + w_u/w_w (R6 numerics) ======
        const int bwg = w - NWG_A;
        const int halfB = bwg >> 5;
        const int grp = tid >> 7, lm = tid & 127;
        const int bB = bwg * 2 + grp;
        float* s_M = (float*)s_big;
        float* s_h2 = s_aux;
        float* s_wr2 = s_aux + 512;
        float wwreg = (lm == 0) ? OMG_C : 0.f;
        float wureg = 0.f;

        for (int t = 0; t < TSTEPS; ++t) {
            if (t > 0) {
                if (wv == 1) wait_flags16(g_fC + (size_t)(t - 1) * NWG_C * FSP, NWG_C, t, lane);
                __syncthreads();
                asm volatile("" ::: "memory");
                float4 mt[32];
                const float4* msrc = (const float4*)&g_M[(size_t)t * MEMN * HSZ];
#pragma unroll
                for (int i = 0; i < 32; ++i) mt[i] = msrc[i * 256 + tid];
                float4* md = (float4*)s_M;
#pragma unroll
                for (int i = 0; i < 32; ++i) md[i * 256 + tid] = mt[i];
            }
            if (wv == 0)
                wait_flags16(g_fA + ((size_t)t * NWG_A + halfB * 32) * FSP, 32, t + 1, lane);
            __syncthreads();
            asm volatile("" ::: "memory");
            s_h2[grp * 256 + lm] = g_hB[((size_t)t * BATCH + bB) * HSZ + lm];
            s_h2[grp * 256 + 128 + lm] = g_hB[((size_t)t * BATCH + bB) * HSZ + 128 + lm];
            __syncthreads();
            const float hv0 = s_h2[grp * 256 + lm], hv1 = s_h2[grp * 256 + lm + 128];
            const float hnorm = sqrtf(grpsum(hv0 * hv0 + hv1 * hv1));
            float sc = 0.f;
            if (t > 0) {
                const float4* mrow = (const float4*)&s_M[(size_t)lm * HSZ];
                const float4* h4 = (const float4*)&s_h2[grp * 256];
                const int sw = lm & 7;
                float a = 0.f;
#pragma unroll 8
                for (int c = 0; c < 64; ++c) {
                    const int ci = c ^ sw;
                    const float4 m4 = mrow[ci], x4 = h4[ci];
                    a += m4.x * x4.x + m4.y * x4.y + m4.z * x4.z + m4.w * x4.w;
                }
                const float mn = g_Mn[(size_t)t * MEMN + lm];
                sc = a / (hnorm * mn + 1e-8f);
            }
            const float mx = grpmax(sc);
            const float ev = expf(sc - mx);
            const float es = grpsum(ev);
            const float wr = ev / es;
            s_wr2[grp * 128 + lm] = wr;
            __syncthreads();
            float rd0 = 0.f, rd1 = 0.f;
            if (t > 0) {
#pragma unroll 8
                for (int m = 0; m < 128; ++m) {
                    const float mv = s_M[m * HSZ + tid];
                    rd0 += s_wr2[m] * mv;
                    rd1 += s_wr2[128 + m] * mv;
                }
            }
            const int b0 = bwg * 2, b1 = b0 + 1;
            float* o0 = out + ((size_t)b0 * TSTEPS + t) * 512;
            float* o1 = out + ((size_t)b1 * TSTEPS + t) * 512;
            o0[tid] = s_h2[tid];
            o1[tid] = s_h2[256 + tid];
            o0[256 + tid] = rd0;
            o1[256 + tid] = rd1;
            const float un = GAMMA_C * wureg + wr + wwreg;
            const float un2 = grpsum(un * un);
            const float us = 1.0f / fmaxf(sqrtf(un2), 1e-12f);
            const float wun = un * us;
            wureg = wun;
            unsigned long long key =
                (((unsigned long long)__float_as_uint(wun)) << 32) | (unsigned)lm;
            const unsigned long long mk = grpminu(key);
            const int amin = (int)(mk & 0xffffffffu);
            const float wwn = GATE_C * wr + ((lm == amin) ? OMG_C : 0.f);
            wwreg = wwn;
            if (t + 1 < TSTEPS)
                st_wt(&g_wwT[((size_t)(t + 1) * MEMN + lm) * BATCH + bB], wwn);
            wait_vm0();
            __syncthreads();
            if (tid == 0) st_flag(&g_fB[((size_t)t * NWG_B + bwg) * FSP], t + 1);
        }
    } else {
        // ====== C: M(t+1) = l2norm(M(t) + ww(t)^T h(t)) (R6 numerics) ======
        const int cwg = w - NWG_A - NWG_B;
        const int m0 = cwg * 4;
        float* s_wwc = s_aux;  // [4][128]
        float mreg[4] = {0.f, 0.f, 0.f, 0.f};

        for (int t = 0; t < TSTEPS - 1; ++t) {
            if (wv == 1 && t > 0)
                wait_flags16(g_fB + (size_t)(t - 1) * NWG_B * FSP, NWG_B, t, lane);
            __syncthreads();
            asm volatile("" ::: "memory");
            {
                const int e0 = tid, e1 = tid + 256;
                float v0, v1;
                if (t > 0) {
                    v0 = g_wwT[((size_t)t * MEMN + m0 + (e0 >> 7)) * BATCH + (e0 & 127)];
                    v1 = g_wwT[((size_t)t * MEMN + m0 + (e1 >> 7)) * BATCH + (e1 & 127)];
                } else {
                    v0 = (m0 + (e0 >> 7) == 0) ? OMG_C : 0.f;
                    v1 = (m0 + (e1 >> 7) == 0) ? OMG_C : 0.f;
                }
                s_wwc[(e0 >> 7) * 128 + (e0 & 127)] = v0;
                s_wwc[(e1 >> 7) * 128 + (e1 & 127)] = v1;
            }
            if (wv == 0) wait_flags16(g_fA + (size_t)t * NWG_A * FSP, NWG_A, t + 1, lane);
            __syncthreads();
            asm volatile("" ::: "memory");
            float4 hb[32];
            const float4* ht4 = (const float4*)&g_hT[((size_t)t * HSZ + tid) * BATCH];
#pragma unroll
            for (int q = 0; q < 32; ++q) hb[q] = ht4[q];
            float macc[4];
#pragma unroll
            for (int mi = 0; mi < 4; ++mi) macc[mi] = mreg[mi];
#pragma unroll
            for (int b4 = 0; b4 < 32; ++b4) {
                const float4 hv4 = hb[b4];
#pragma unroll
                for (int mi = 0; mi < 4; ++mi) {
                    const float* wc = &s_wwc[mi * 128 + b4 * 4];
                    macc[mi] += wc[0] * hv4.x + wc[1] * hv4.y + wc[2] * hv4.z + wc[3] * hv4.w;
                }
            }
            float nr[4];
            red256sum4(macc[0] * macc[0], macc[1] * macc[1],
                       macc[2] * macc[2], macc[3] * macc[3], nr);
#pragma unroll
            for (int mi = 0; mi < 4; ++mi) {
                const float nrm = sqrtf(nr[mi]);
                const float scale = 1.0f / fmaxf(nrm, 1e-12f);
                const float vo = macc[mi] * scale;
                mreg[mi] = vo;
                st_wt(&g_M[((size_t)(t + 1) * MEMN + m0 + mi) * HSZ + tid], vo);
                if (tid == 0) st_wt(&g_Mn[(size_t)(t + 1) * MEMN + m0 + mi], nrm * scale);
            }
            wait_vm0();
            __syncthreads();
            if (tid == 0) st_flag(&g_fC[((size_t)t * NWG_C + cwg) * FSP], t + 1);
        }
    }
}

extern "C" void kernel_launch(void* const* d_in, const int* in_sizes, int n_in,
                              void* d_out, int out_size, void* d_ws, size_t ws_size,
                              hipStream_t stream) {
    const float* X   = (const float*)d_in[0];
    const float* Wih = (const float*)d_in[1];
    const float* Whh = (const float*)d_in[2];
    const float* bih = (const float*)d_in[3];
    const float* bhh = (const float*)d_in[4];
    float* out = (float*)d_out;
    (void)in_sizes; (void)n_in; (void)out_size; (void)d_ws; (void)ws_size;

    hipLaunchKernelGGL(reset_ctrl_kernel, dim3(1024), dim3(256), 0, stream);
    hipLaunchKernelGGL(pre_kernel, dim3(2048), dim3(NTHR), 0, stream, X, Wih, bih, bhh);
    hipLaunchKernelGGL(mann_persist, dim3(NWG), dim3(NTHR), 0, stream, Whh, out);
}